// Round 3
// baseline (1248.563 us; speedup 1.0000x reference)
//
#include <hip/hip_runtime.h>
#include <hip/hip_bf16.h>

#define T 2048
#define C 4096
#define H 32
#define KVH 8
#define D 128
// rep = H/KVH = 4

typedef __bf16 bf16x8 __attribute__((ext_vector_type(8)));
typedef __bf16 bf16x4 __attribute__((ext_vector_type(4)));
typedef float floatx4 __attribute__((ext_vector_type(4)));

#define MFMA16 __builtin_amdgcn_mfma_f32_16x16x32_bf16

// ---------------- split-bf16 MFMA GEMM ------------------------------------
// Cm[M][N] = A[M][K] @ B[K][N], fp32 in/out. A is always decomposed into
// hi+lo bf16. NTERMS=3: B also hi/lo, product = hh + lh + hl (~2^-17 rel
// error; needed where results get exponentiated: q,k). NTERMS=2: B plain
// bf16, product = hh + lh = A*B_hi (~2^-9 rel error on B only; fine for
// linear paths: v, y). 128x128 tile, BK=32, 4 waves (2x2), each wave 4x4
// frags of 16x16x32 MFMA.
template <int NTERMS>
__device__ __forceinline__ void gemm_split_body(
    const float* __restrict__ A, const float* __restrict__ B,
    float* __restrict__ Cm, int N, int K, int row0, int col0) {
  __shared__ __bf16 Ah[128][40], Al[128][40], Bh[128][40];
  __shared__ __bf16 Bl[NTERMS == 3 ? 128 : 1][NTERMS == 3 ? 40 : 1];
  const int tid = threadIdx.x;
  const int lane = tid & 63;
  const int w = tid >> 6;
  const int n16 = lane & 15;
  const int quad = lane >> 4;
  const int wm = w >> 1, wn = w & 1;

  floatx4 acc[4][4];
#pragma unroll
  for (int mi = 0; mi < 4; ++mi)
#pragma unroll
    for (int ni = 0; ni < 4; ++ni) acc[mi][ni] = (floatx4){0.f, 0.f, 0.f, 0.f};

  const int ar = tid >> 3;        // A row within 32-row group
  const int ak = (tid & 7) * 4;   // A k-quad (0,4,..,28)
  const int bg = tid >> 7;        // B k-group (0..1)
  const int bn = tid & 127;       // B col within tile

  for (int k0 = 0; k0 < K; k0 += 32) {
    // ---- stage A (128x32 fp32 -> hi/lo bf16, row-major [m][k]) ----
#pragma unroll
    for (int p = 0; p < 4; ++p) {
      const int r = p * 32 + ar;
      const float4 av = *(const float4*)(A + (size_t)(row0 + r) * K + k0 + ak);
      bf16x4 h, l;
      h[0] = (__bf16)av.x; l[0] = (__bf16)(av.x - (float)h[0]);
      h[1] = (__bf16)av.y; l[1] = (__bf16)(av.y - (float)h[1]);
      h[2] = (__bf16)av.z; l[2] = (__bf16)(av.z - (float)h[2]);
      h[3] = (__bf16)av.w; l[3] = (__bf16)(av.w - (float)h[3]);
      *(bf16x4*)(&Ah[r][ak]) = h;
      *(bf16x4*)(&Al[r][ak]) = l;
    }
    // ---- stage B (32x128 fp32 -> transposed LDS [n][k]) ----
#pragma unroll
    for (int p = 0; p < 4; ++p) {
      const int kb = bg * 16 + p * 4;
      const float* bp = B + (size_t)(k0 + kb) * N + col0 + bn;
      const float f0 = bp[0];
      const float f1 = bp[(size_t)N];
      const float f2 = bp[(size_t)2 * N];
      const float f3 = bp[(size_t)3 * N];
      bf16x4 h;
      h[0] = (__bf16)f0;
      h[1] = (__bf16)f1;
      h[2] = (__bf16)f2;
      h[3] = (__bf16)f3;
      *(bf16x4*)(&Bh[bn][kb]) = h;
      if constexpr (NTERMS == 3) {
        bf16x4 l;
        l[0] = (__bf16)(f0 - (float)h[0]);
        l[1] = (__bf16)(f1 - (float)h[1]);
        l[2] = (__bf16)(f2 - (float)h[2]);
        l[3] = (__bf16)(f3 - (float)h[3]);
        *(bf16x4*)(&Bl[bn][kb]) = l;
      }
    }
    __syncthreads();
    // ---- fragments + MFMAs ----
    bf16x8 a_h[4], a_l[4], b_h[4], b_l[4];
#pragma unroll
    for (int mi = 0; mi < 4; ++mi) {
      a_h[mi] = *(const bf16x8*)(&Ah[wm * 64 + mi * 16 + n16][quad * 8]);
      a_l[mi] = *(const bf16x8*)(&Al[wm * 64 + mi * 16 + n16][quad * 8]);
    }
#pragma unroll
    for (int ni = 0; ni < 4; ++ni) {
      b_h[ni] = *(const bf16x8*)(&Bh[wn * 64 + ni * 16 + n16][quad * 8]);
      if constexpr (NTERMS == 3)
        b_l[ni] = *(const bf16x8*)(&Bl[wn * 64 + ni * 16 + n16][quad * 8]);
    }
#pragma unroll
    for (int mi = 0; mi < 4; ++mi)
#pragma unroll
      for (int ni = 0; ni < 4; ++ni) {
        acc[mi][ni] = MFMA16(a_h[mi], b_h[ni], acc[mi][ni], 0, 0, 0);
        acc[mi][ni] = MFMA16(a_l[mi], b_h[ni], acc[mi][ni], 0, 0, 0);
        if constexpr (NTERMS == 3)
          acc[mi][ni] = MFMA16(a_h[mi], b_l[ni], acc[mi][ni], 0, 0, 0);
      }
    __syncthreads();
  }
  // ---- epilogue: C-layout row = quad*4+i, col = n16 ----
#pragma unroll
  for (int mi = 0; mi < 4; ++mi)
#pragma unroll
    for (int i = 0; i < 4; ++i) {
      const int r = row0 + wm * 64 + mi * 16 + quad * 4 + i;
      float* cp = Cm + (size_t)r * N + col0 + wn * 64 + n16;
#pragma unroll
      for (int ni = 0; ni < 4; ++ni) cp[ni * 16] = acc[mi][ni][i];
    }
}

template <int NTERMS>
__global__ __launch_bounds__(256) void gemm_split_t(
    const float* __restrict__ A, const float* __restrict__ B,
    float* __restrict__ Cm, int N, int K) {
  gemm_split_body<NTERMS>(A, B, Cm, N, K, blockIdx.y * 128, blockIdx.x * 128);
}

// All three projections fused into one 768-block launch (3 blocks/CU ->
// MFMA/VALU overlap across blocks). Wq,Wk: 3-term; Wv: 2-term (linear path).
__global__ __launch_bounds__(256) void gemm_qkv(
    const float* __restrict__ x, const float* __restrict__ Wq,
    const float* __restrict__ Wk, const float* __restrict__ Wv,
    float* __restrict__ q_ws, float* __restrict__ k_ws,
    float* __restrict__ v_ws) {
  const int bx = blockIdx.x;
  const int row0 = blockIdx.y * 128;
  if (bx < 32) {
    gemm_split_body<3>(x, Wq, q_ws, H * D, C, row0, bx * 128);
  } else if (bx < 40) {
    gemm_split_body<3>(x, Wk, k_ws, KVH * D, C, row0, (bx - 32) * 128);
  } else {
    gemm_split_body<2>(x, Wv, v_ws, KVH * D, C, row0, (bx - 40) * 128);
  }
}

// ---------------- RoPE in-place on q (T x H*D) and k (T x KVH*D) ----------
__global__ __launch_bounds__(256) void rope_kernel(
    float* __restrict__ q, float* __restrict__ k,
    const float* __restrict__ cosb,
    const float* __restrict__ sinb) {
  int idx = blockIdx.x * 256 + threadIdx.x;
  int total = T * (H + KVH) * (D / 2);
  if (idx >= total) return;
  int d = idx % (D / 2);
  int rest = idx / (D / 2);
  int head = rest % (H + KVH);
  int t = rest / (H + KVH);
  float cv = cosb[(size_t)t * D + d];
  float sv = sinb[(size_t)t * D + d];
  float* base;
  if (head < H) base = q + (size_t)t * (H * D) + head * D;
  else          base = k + (size_t)t * (KVH * D) + (head - H) * D;
  float u1 = base[d];
  float u2 = base[d + D / 2];
  base[d]         = u1 * cv - u2 * sv;
  base[d + D / 2] = u2 * cv + u1 * sv;
}

// ---- k: emit out_k (fp32 [kvh][t][d]) + khi/klo (bf16 split, same layout) ----
__global__ __launch_bounds__(256) void convert_k(
    const float* __restrict__ k_ws, float* __restrict__ out_k,
    __bf16* __restrict__ khi, __bf16* __restrict__ klo) {
  int idx = blockIdx.x * 256 + threadIdx.x;
  if (idx >= KVH * T * D) return;
  int d = idx & (D - 1);
  int t = (idx >> 7) & (T - 1);
  int kvh = idx >> 18;
  float f = k_ws[(size_t)t * (KVH * D) + kvh * D + d];
  out_k[idx] = f;                      // idx == ((kvh*T)+t)*D + d
  __bf16 hi = (__bf16)f;
  khi[idx] = hi;
  klo[idx] = (__bf16)(f - (float)hi);
}

// ---- v: emit out_v (fp32 [kvh][t][d]) + vt (bf16 transposed [kvh][d][t]) ----
__global__ __launch_bounds__(256) void convert_v(
    const float* __restrict__ v_ws, float* __restrict__ out_v,
    __bf16* __restrict__ vt) {
  __shared__ __bf16 tile[64][65];
  const int t0 = blockIdx.x * 64;
  const int d0 = blockIdx.y * 64;
  const int kvh = blockIdx.z;
#pragma unroll
  for (int p = 0; p < 16; ++p) {
    int i = p * 256 + threadIdx.x;
    int r = i >> 6;      // t offset
    int c = i & 63;      // d offset (consecutive tid -> coalesced)
    float f = v_ws[(size_t)(t0 + r) * (KVH * D) + kvh * D + d0 + c];
    out_v[((size_t)kvh * T + t0 + r) * D + d0 + c] = f;
    tile[r][c] = (__bf16)f;
  }
  __syncthreads();
#pragma unroll
  for (int p = 0; p < 16; ++p) {
    int i = p * 256 + threadIdx.x;
    int dd = i >> 6;     // d offset
    int tt = i & 63;     // t offset (consecutive tid -> coalesced)
    vt[((size_t)kvh * D + d0 + dd) * T + t0 + tt] = tile[tt][dd];
  }
}

// ---------------- MFMA flash attention, balanced + LDS-staged --------------
// Grid (T/128, H); block bx owns Q-blocks p_lo=bx and p_hi=31-bx (light+heavy
// pairing -> uniform per-block compute). 4 waves; wave w owns 16-row strips
// of BOTH Q-blocks. Per KV step the whole block cooperatively stages K(hi+lo)
// and V tiles into double-buffered LDS (issue loads for t+1 before compute of
// t, ds_write after, ONE barrier per tile). T13 defer-max skips O-rescale
// unless the tile max grows by >8; T5 setprio around MFMA clusters.
struct StageRegs { bf16x8 k0, k1, l0, l1, v0, v1; };

__device__ __forceinline__ void stage_load(
    StageRegs& s, const __bf16* __restrict__ Kh, const __bf16* __restrict__ Kl,
    const __bf16* __restrict__ Vt, int j0, int tid) {
  const int kr = tid >> 4, kj = (tid & 15) * 8;
  s.k0 = *(const bf16x8*)(Kh + (size_t)(j0 + kr) * D + kj);
  s.k1 = *(const bf16x8*)(Kh + (size_t)(j0 + kr + 16) * D + kj);
  s.l0 = *(const bf16x8*)(Kl + (size_t)(j0 + kr) * D + kj);
  s.l1 = *(const bf16x8*)(Kl + (size_t)(j0 + kr + 16) * D + kj);
  const int vd = tid >> 2, vj = (tid & 3) * 8;
  s.v0 = *(const bf16x8*)(Vt + (size_t)vd * T + j0 + vj);
  s.v1 = *(const bf16x8*)(Vt + (size_t)(vd + 64) * T + j0 + vj);
}

__device__ __forceinline__ void stage_write(
    const StageRegs& s, __bf16* __restrict__ KhL, __bf16* __restrict__ KlL,
    __bf16* __restrict__ VL, int tid) {
  const int kr = tid >> 4, kj = (tid & 15) * 8;
  *(bf16x8*)(KhL + kr * 136 + kj) = s.k0;
  *(bf16x8*)(KhL + (kr + 16) * 136 + kj) = s.k1;
  *(bf16x8*)(KlL + kr * 136 + kj) = s.l0;
  *(bf16x8*)(KlL + (kr + 16) * 136 + kj) = s.l1;
  const int vd = tid >> 2, vj = (tid & 3) * 8;
  *(bf16x8*)(VL + vd * 40 + vj) = s.v0;
  *(bf16x8*)(VL + (vd + 64) * 40 + vj) = s.v1;
}

__device__ __forceinline__ void softmax_pv(
    floatx4 s0, floatx4 s1,
    const __bf16* __restrict__ VT, __bf16* __restrict__ Pw,
    floatx4* __restrict__ O, float* __restrict__ m_i, float* __restrict__ l_i,
    int j0, int r_base, int n16, int quad) {
  // causal mask (wave-uniform branch; C-layout rows r = r_base + quad*4 + i)
  if (j0 + 31 > r_base) {
#pragma unroll
    for (int i = 0; i < 4; ++i) {
      int r = r_base + quad * 4 + i;
      if (j0 + n16 > r) s0[i] = -INFINITY;
      if (j0 + 16 + n16 > r) s1[i] = -INFINITY;
    }
  }
  float p0[4], p1[4];
#pragma unroll
  for (int i = 0; i < 4; ++i) {
    float mt = fmaxf(s0[i], s1[i]);
    mt = fmaxf(mt, __shfl_xor(mt, 1));
    mt = fmaxf(mt, __shfl_xor(mt, 2));
    mt = fmaxf(mt, __shfl_xor(mt, 4));
    mt = fmaxf(mt, __shfl_xor(mt, 8));
    // defer-max (T13): rescale only when tile max exceeds running max by >8.
    // P values are then bounded by e^8 instead of 1 (fp32/bf16 tolerate).
    // First tile: m_i=-inf -> m_i+8=-inf -> condition true; alpha=exp(-inf)=0.
    if (mt > m_i[i] + 8.0f) {
      float alpha = __expf(m_i[i] - mt);
      m_i[i] = mt;
      l_i[i] *= alpha;
#pragma unroll
      for (int dt = 0; dt < 8; ++dt) O[dt][i] *= alpha;
    }
    p0[i] = __expf(s0[i] - m_i[i]);
    p1[i] = __expf(s1[i] - m_i[i]);
    float rs = p0[i] + p1[i];
    rs += __shfl_xor(rs, 1);
    rs += __shfl_xor(rs, 2);
    rs += __shfl_xor(rs, 4);
    rs += __shfl_xor(rs, 8);
    l_i[i] += rs;
  }
  // P: C-layout -> A-layout via per-wave LDS round-trip (no barrier needed)
#pragma unroll
  for (int i = 0; i < 4; ++i) {
    Pw[(quad * 4 + i) * 40 + n16] = (__bf16)p0[i];
    Pw[(quad * 4 + i) * 40 + n16 + 16] = (__bf16)p1[i];
  }
  bf16x8 pA = *(const bf16x8*)(Pw + n16 * 40 + quad * 8);
  __builtin_amdgcn_s_setprio(1);
#pragma unroll
  for (int dt = 0; dt < 8; ++dt) {
    bf16x8 vB = *(const bf16x8*)(VT + (dt * 16 + n16) * 40 + quad * 8);
    O[dt] = MFMA16(pA, vB, O[dt], 0, 0, 0);
  }
  __builtin_amdgcn_s_setprio(0);
}

template <bool BOTH>
__device__ __forceinline__ void attn_tile2(
    const __bf16* __restrict__ KhT, const __bf16* __restrict__ KlT,
    const __bf16* __restrict__ VT, __bf16* __restrict__ Pw,
    const bf16x8* qh_hi, const bf16x8* ql_hi,
    const bf16x8* qh_lo, const bf16x8* ql_lo,
    floatx4* O_hi, float* m_hi, float* l_hi,
    floatx4* O_lo, float* m_lo, float* l_lo,
    int j0, int rb_hi, int rb_lo, int n16, int quad) {
  floatx4 sh0 = {0.f, 0.f, 0.f, 0.f}, sh1 = {0.f, 0.f, 0.f, 0.f};
  floatx4 sl0 = {0.f, 0.f, 0.f, 0.f}, sl1 = {0.f, 0.f, 0.f, 0.f};
  __builtin_amdgcn_s_setprio(1);
#pragma unroll
  for (int c = 0; c < 4; ++c) {
    const int off = c * 32 + quad * 8;
    bf16x8 k0h = *(const bf16x8*)(KhT + n16 * 136 + off);
    bf16x8 k1h = *(const bf16x8*)(KhT + (n16 + 16) * 136 + off);
    bf16x8 k0l = *(const bf16x8*)(KlT + n16 * 136 + off);
    bf16x8 k1l = *(const bf16x8*)(KlT + (n16 + 16) * 136 + off);
    sh0 = MFMA16(qh_hi[c], k0h, sh0, 0, 0, 0);
    sh0 = MFMA16(ql_hi[c], k0h, sh0, 0, 0, 0);
    sh0 = MFMA16(qh_hi[c], k0l, sh0, 0, 0, 0);
    sh1 = MFMA16(qh_hi[c], k1h, sh1, 0, 0, 0);
    sh1 = MFMA16(ql_hi[c], k1h, sh1, 0, 0, 0);
    sh1 = MFMA16(qh_hi[c], k1l, sh1, 0, 0, 0);
    if (BOTH) {
      sl0 = MFMA16(qh_lo[c], k0h, sl0, 0, 0, 0);
      sl0 = MFMA16(ql_lo[c], k0h, sl0, 0, 0, 0);
      sl0 = MFMA16(qh_lo[c], k0l, sl0, 0, 0, 0);
      sl1 = MFMA16(qh_lo[c], k1h, sl1, 0, 0, 0);
      sl1 = MFMA16(ql_lo[c], k1h, sl1, 0, 0, 0);
      sl1 = MFMA16(qh_lo[c], k1l, sl1, 0, 0, 0);
    }
  }
  __builtin_amdgcn_s_setprio(0);
  softmax_pv(sh0, sh1, VT, Pw, O_hi, m_hi, l_hi, j0, rb_hi, n16, quad);
  if (BOTH) softmax_pv(sl0, sl1, VT, Pw, O_lo, m_lo, l_lo, j0, rb_lo, n16, quad);
}

__global__ __launch_bounds__(256, 2) void flash_attn(
    float* __restrict__ q,
    const __bf16* __restrict__ khi,   // [KVH][T][D]
    const __bf16* __restrict__ klo,   // [KVH][T][D]
    const __bf16* __restrict__ vt) {  // [KVH][D][T]
  __shared__ __attribute__((aligned(16))) __bf16 KhL[2][32 * 136];
  __shared__ __attribute__((aligned(16))) __bf16 KlL[2][32 * 136];
  __shared__ __attribute__((aligned(16))) __bf16 VL[2][128 * 40];
  __shared__ __attribute__((aligned(16))) __bf16 Pst[4][16 * 40];

  const int tid = threadIdx.x;
  const int w = tid >> 6;
  const int lane = tid & 63;
  const int n16 = lane & 15;
  const int quad = lane >> 4;
  const int h = blockIdx.y;
  const int kvh = h >> 2;
  const int p_lo = blockIdx.x;         // 0..15
  const int p_hi = 31 - p_lo;          // 16..31
  const int rb_lo = p_lo * 64 + w * 16;
  const int rb_hi = p_hi * 64 + w * 16;
  const int nt = 64 - 2 * p_lo;              // block-uniform loop count
  const int nt_lo = (rb_lo + 15) / 32 + 1;   // wave-uniform strip bounds
  const int nt_hi = (rb_hi + 15) / 32 + 1;

  const __bf16* Kh = khi + (size_t)kvh * T * D;
  const __bf16* Kl = klo + (size_t)kvh * T * D;
  const __bf16* Vt = vt + (size_t)kvh * D * T;

  // Q fragments (both strips), A-layout: row m = n16, k = c*32 + quad*8 + jj
  bf16x8 qh_lo[4], ql_lo[4], qh_hi[4], ql_hi[4];
  {
    const float* qr_lo = q + (size_t)(rb_lo + n16) * C + h * D;
    const float* qr_hi = q + (size_t)(rb_hi + n16) * C + h * D;
#pragma unroll
    for (int c = 0; c < 4; ++c) {
      const float4 a0 = *(const float4*)(qr_lo + c * 32 + quad * 8);
      const float4 a1 = *(const float4*)(qr_lo + c * 32 + quad * 8 + 4);
      const float4 b0 = *(const float4*)(qr_hi + c * 32 + quad * 8);
      const float4 b1 = *(const float4*)(qr_hi + c * 32 + quad * 8 + 4);
      const float fl[8] = {a0.x, a0.y, a0.z, a0.w, a1.x, a1.y, a1.z, a1.w};
      const float fh[8] = {b0.x, b0.y, b0.z, b0.w, b1.x, b1.y, b1.z, b1.w};
#pragma unroll
      for (int jj = 0; jj < 8; ++jj) {
        __bf16 hl = (__bf16)fl[jj];
        qh_lo[c][jj] = hl;
        ql_lo[c][jj] = (__bf16)(fl[jj] - (float)hl);
        __bf16 hh = (__bf16)fh[jj];
        qh_hi[c][jj] = hh;
        ql_hi[c][jj] = (__bf16)(fh[jj] - (float)hh);
      }
    }
  }

  floatx4 O_lo[8], O_hi[8];
#pragma unroll
  for (int dt = 0; dt < 8; ++dt) {
    O_lo[dt] = (floatx4){0.f, 0.f, 0.f, 0.f};
    O_hi[dt] = (floatx4){0.f, 0.f, 0.f, 0.f};
  }
  float m_lo[4] = {-INFINITY, -INFINITY, -INFINITY, -INFINITY};
  float m_hi[4] = {-INFINITY, -INFINITY, -INFINITY, -INFINITY};
  float l_lo[4] = {0.f, 0.f, 0.f, 0.f};
  float l_hi[4] = {0.f, 0.f, 0.f, 0.f};

  // prologue: stage tile 0 into buffer 0
  StageRegs sreg;
  stage_load(sreg, Kh, Kl, Vt, 0, tid);
  stage_write(sreg, KhL[0], KlL[0], VL[0], tid);
  __syncthreads();

  __bf16* Pw = Pst[w];
  for (int t = 0; t < nt; ++t) {
    const int cur = t & 1;
    const int j0 = t * 32;
    if (t + 1 < nt) stage_load(sreg, Kh, Kl, Vt, j0 + 32, tid);   // issue early
    if (t < nt_hi) {                                              // wave-uniform
      if (t < nt_lo)
        attn_tile2<true>(KhL[cur], KlL[cur], VL[cur], Pw,
                         qh_hi, ql_hi, qh_lo, ql_lo,
                         O_hi, m_hi, l_hi, O_lo, m_lo, l_lo,
                         j0, rb_hi, rb_lo, n16, quad);
      else
        attn_tile2<false>(KhL[cur], KlL[cur], VL[cur], Pw,
                          qh_hi, ql_hi, qh_lo, ql_lo,
                          O_hi, m_hi, l_hi, O_lo, m_lo, l_lo,
                          j0, rb_hi, rb_lo, n16, quad);
    }
    if (t + 1 < nt) stage_write(sreg, KhL[cur ^ 1], KlL[cur ^ 1], VL[cur ^ 1], tid);
    __syncthreads();   // writes visible before next compute; readers of cur done
  }

  // epilogue: y = O / l, overwrite q rows in place (both strips)
#pragma unroll
  for (int i = 0; i < 4; ++i) {
    float inv_l = 1.0f / l_lo[i];
    float inv_h = 1.0f / l_hi[i];
    int r_l = rb_lo + quad * 4 + i;
    int r_h = rb_hi + quad * 4 + i;
    float* yl = q + (size_t)r_l * C + h * D + n16;
    float* yh = q + (size_t)r_h * C + h * D + n16;
#pragma unroll
    for (int dt = 0; dt < 8; ++dt) {
      yl[dt * 16] = O_lo[dt][i] * inv_l;
      yh[dt * 16] = O_hi[dt][i] * inv_h;
    }
  }
}

extern "C" void kernel_launch(void* const* d_in, const int* in_sizes, int n_in,
                              void* d_out, int out_size, void* d_ws, size_t ws_size,
                              hipStream_t stream) {
  (void)in_sizes; (void)n_in; (void)out_size; (void)ws_size;
  const float* x    = (const float*)d_in[0];
  const float* Wq   = (const float*)d_in[1];
  const float* Wk   = (const float*)d_in[2];
  const float* Wv   = (const float*)d_in[3];
  const float* Wo   = (const float*)d_in[4];
  const float* cosb = (const float*)d_in[5];
  const float* sinb = (const float*)d_in[6];
  // d_in[7] = mask: unused (causal structure applied exactly)

  // workspace layout (~60 MB)
  float* q_ws = (float*)d_ws;                         // T*C fp32 (q, then y in-place)
  float* k_ws = q_ws + (size_t)T * C;                 // T*KVH*D fp32
  float* v_ws = k_ws + (size_t)T * KVH * D;           // T*KVH*D fp32
  __bf16* khi = (__bf16*)(v_ws + (size_t)T * KVH * D);          // 4 MB
  __bf16* klo = khi + (size_t)KVH * T * D;                      // 4 MB
  __bf16* vt  = klo + (size_t)KVH * T * D;                      // 4 MB

  float* out_y = (float*)d_out;
  float* out_k = out_y + (size_t)T * C;
  float* out_v = out_k + (size_t)KVH * T * D;

  dim3 blk(256);
  // fused Q/K/V projections: 768 blocks, 3/CU
  gemm_qkv<<<dim3(48, T / 128), blk, 0, stream>>>(x, Wq, Wk, Wv, q_ws, k_ws, v_ws);
  // rope on q and k (in place)
  int rope_total = T * (H + KVH) * (D / 2);
  rope_kernel<<<(rope_total + 255) / 256, blk, 0, stream>>>(q_ws, k_ws, cosb, sinb);
  // conversions + kv outputs
  convert_k<<<(KVH * T * D) / 256, blk, 0, stream>>>(k_ws, out_k, khi, klo);
  convert_v<<<dim3(T / 64, D / 64, KVH), blk, 0, stream>>>(v_ws, out_v, vt);
  // flash attention (balanced, LDS-staged; writes y over q_ws)
  flash_attn<<<dim3(16, H), blk, 0, stream>>>(q_ws, khi, klo, vt);
  // output projection: 2-term split (linear path)
  gemm_split_t<2><<<dim3(C / 128, T / 128), blk, 0, stream>>>(q_ws, Wo, out_y, C, C);
}

// Round 4
// 904.037 us; speedup vs baseline: 1.3811x; 1.3811x over previous
//
#include <hip/hip_runtime.h>
#include <hip/hip_bf16.h>

#define T 2048
#define C 4096
#define H 32
#define KVH 8
#define D 128
// rep = H/KVH = 4

typedef __bf16 bf16x8 __attribute__((ext_vector_type(8)));
typedef __bf16 bf16x4 __attribute__((ext_vector_type(4)));
typedef float floatx4 __attribute__((ext_vector_type(4)));

#define MFMA16 __builtin_amdgcn_mfma_f32_16x16x32_bf16

// ---------------- split-bf16 MFMA GEMM ------------------------------------
// Cm[M][N] = A[M][K] @ B[K][N], fp32 in/out. A is always decomposed into
// hi+lo bf16. NTERMS=3: B also hi/lo, product = hh + lh + hl (~2^-17 rel
// error; needed where results get exponentiated: q,k). NTERMS=2: B plain
// bf16, product = hh + lh = A*B_hi (~2^-9 rel error on B only; fine for
// linear paths: v, y). 128x128 tile, BK=32, 4 waves (2x2), each wave 4x4
// frags of 16x16x32 MFMA.
template <int NTERMS>
__device__ __forceinline__ void gemm_split_body(
    const float* __restrict__ A, const float* __restrict__ B,
    float* __restrict__ Cm, int N, int K, int row0, int col0) {
  __shared__ __bf16 Ah[128][40], Al[128][40], Bh[128][40];
  __shared__ __bf16 Bl[NTERMS == 3 ? 128 : 1][NTERMS == 3 ? 40 : 1];
  const int tid = threadIdx.x;
  const int lane = tid & 63;
  const int w = tid >> 6;
  const int n16 = lane & 15;
  const int quad = lane >> 4;
  const int wm = w >> 1, wn = w & 1;

  floatx4 acc[4][4];
#pragma unroll
  for (int mi = 0; mi < 4; ++mi)
#pragma unroll
    for (int ni = 0; ni < 4; ++ni) acc[mi][ni] = (floatx4){0.f, 0.f, 0.f, 0.f};

  const int ar = tid >> 3;        // A row within 32-row group
  const int ak = (tid & 7) * 4;   // A k-quad (0,4,..,28)
  const int bg = tid >> 7;        // B k-group (0..1)
  const int bn = tid & 127;       // B col within tile

  for (int k0 = 0; k0 < K; k0 += 32) {
    // ---- stage A (128x32 fp32 -> hi/lo bf16, row-major [m][k]) ----
#pragma unroll
    for (int p = 0; p < 4; ++p) {
      const int r = p * 32 + ar;
      const float4 av = *(const float4*)(A + (size_t)(row0 + r) * K + k0 + ak);
      bf16x4 h, l;
      h[0] = (__bf16)av.x; l[0] = (__bf16)(av.x - (float)h[0]);
      h[1] = (__bf16)av.y; l[1] = (__bf16)(av.y - (float)h[1]);
      h[2] = (__bf16)av.z; l[2] = (__bf16)(av.z - (float)h[2]);
      h[3] = (__bf16)av.w; l[3] = (__bf16)(av.w - (float)h[3]);
      *(bf16x4*)(&Ah[r][ak]) = h;
      *(bf16x4*)(&Al[r][ak]) = l;
    }
    // ---- stage B (32x128 fp32 -> transposed LDS [n][k]) ----
#pragma unroll
    for (int p = 0; p < 4; ++p) {
      const int kb = bg * 16 + p * 4;
      const float* bp = B + (size_t)(k0 + kb) * N + col0 + bn;
      const float f0 = bp[0];
      const float f1 = bp[(size_t)N];
      const float f2 = bp[(size_t)2 * N];
      const float f3 = bp[(size_t)3 * N];
      bf16x4 h;
      h[0] = (__bf16)f0;
      h[1] = (__bf16)f1;
      h[2] = (__bf16)f2;
      h[3] = (__bf16)f3;
      *(bf16x4*)(&Bh[bn][kb]) = h;
      if constexpr (NTERMS == 3) {
        bf16x4 l;
        l[0] = (__bf16)(f0 - (float)h[0]);
        l[1] = (__bf16)(f1 - (float)h[1]);
        l[2] = (__bf16)(f2 - (float)h[2]);
        l[3] = (__bf16)(f3 - (float)h[3]);
        *(bf16x4*)(&Bl[bn][kb]) = l;
      }
    }
    __syncthreads();
    // ---- fragments + MFMAs ----
    bf16x8 a_h[4], a_l[4], b_h[4], b_l[4];
#pragma unroll
    for (int mi = 0; mi < 4; ++mi) {
      a_h[mi] = *(const bf16x8*)(&Ah[wm * 64 + mi * 16 + n16][quad * 8]);
      a_l[mi] = *(const bf16x8*)(&Al[wm * 64 + mi * 16 + n16][quad * 8]);
    }
#pragma unroll
    for (int ni = 0; ni < 4; ++ni) {
      b_h[ni] = *(const bf16x8*)(&Bh[wn * 64 + ni * 16 + n16][quad * 8]);
      if constexpr (NTERMS == 3)
        b_l[ni] = *(const bf16x8*)(&Bl[wn * 64 + ni * 16 + n16][quad * 8]);
    }
#pragma unroll
    for (int mi = 0; mi < 4; ++mi)
#pragma unroll
      for (int ni = 0; ni < 4; ++ni) {
        acc[mi][ni] = MFMA16(a_h[mi], b_h[ni], acc[mi][ni], 0, 0, 0);
        acc[mi][ni] = MFMA16(a_l[mi], b_h[ni], acc[mi][ni], 0, 0, 0);
        if constexpr (NTERMS == 3)
          acc[mi][ni] = MFMA16(a_h[mi], b_l[ni], acc[mi][ni], 0, 0, 0);
      }
    __syncthreads();
  }
  // ---- epilogue: C-layout row = quad*4+i, col = n16 ----
#pragma unroll
  for (int mi = 0; mi < 4; ++mi)
#pragma unroll
    for (int i = 0; i < 4; ++i) {
      const int r = row0 + wm * 64 + mi * 16 + quad * 4 + i;
      float* cp = Cm + (size_t)r * N + col0 + wn * 64 + n16;
#pragma unroll
      for (int ni = 0; ni < 4; ++ni) cp[ni * 16] = acc[mi][ni][i];
    }
}

template <int NTERMS>
__global__ __launch_bounds__(256) void gemm_split_t(
    const float* __restrict__ A, const float* __restrict__ B,
    float* __restrict__ Cm, int N, int K) {
  gemm_split_body<NTERMS>(A, B, Cm, N, K, blockIdx.y * 128, blockIdx.x * 128);
}

// All three projections fused into one 768-block launch (3 blocks/CU ->
// MFMA/VALU overlap across blocks). Wq,Wk: 3-term; Wv: 2-term (linear path).
__global__ __launch_bounds__(256) void gemm_qkv(
    const float* __restrict__ x, const float* __restrict__ Wq,
    const float* __restrict__ Wk, const float* __restrict__ Wv,
    float* __restrict__ q_ws, float* __restrict__ k_ws,
    float* __restrict__ v_ws) {
  const int bx = blockIdx.x;
  const int row0 = blockIdx.y * 128;
  if (bx < 32) {
    gemm_split_body<3>(x, Wq, q_ws, H * D, C, row0, bx * 128);
  } else if (bx < 40) {
    gemm_split_body<3>(x, Wk, k_ws, KVH * D, C, row0, (bx - 32) * 128);
  } else {
    gemm_split_body<2>(x, Wv, v_ws, KVH * D, C, row0, (bx - 40) * 128);
  }
}

// ---- k: RoPE + emit out_k (fp32 [kvh][t][d]) + khi/klo (bf16 split) ------
// One thread per (kvh, t, d<64) pair; applies rope to the (d, d+64) pair.
// cos[t][d+64] == cos[t][d] (table is concat([freqs, freqs])).
__global__ __launch_bounds__(256) void convert_k(
    const float* __restrict__ k_ws, float* __restrict__ out_k,
    __bf16* __restrict__ khi, __bf16* __restrict__ klo,
    const float* __restrict__ cosb, const float* __restrict__ sinb) {
  int idx = blockIdx.x * 256 + threadIdx.x;
  if (idx >= KVH * T * 64) return;
  int d = idx & 63;
  int t = (idx >> 6) & (T - 1);
  int kvh = idx >> 17;
  const float* kp = k_ws + (size_t)t * (KVH * D) + kvh * D;
  float u1 = kp[d];
  float u2 = kp[d + 64];
  float cv = cosb[(size_t)t * D + d];
  float sv = sinb[(size_t)t * D + d];
  float r1 = u1 * cv - u2 * sv;
  float r2 = u2 * cv + u1 * sv;
  size_t base = ((size_t)kvh * T + t) * D + d;
  out_k[base] = r1;
  out_k[base + 64] = r2;
  __bf16 h1 = (__bf16)r1;
  khi[base] = h1;
  klo[base] = (__bf16)(r1 - (float)h1);
  __bf16 h2 = (__bf16)r2;
  khi[base + 64] = h2;
  klo[base + 64] = (__bf16)(r2 - (float)h2);
}

// ---- v: emit out_v (fp32 [kvh][t][d]) + vt (bf16 transposed [kvh][d][t]) ----
__global__ __launch_bounds__(256) void convert_v(
    const float* __restrict__ v_ws, float* __restrict__ out_v,
    __bf16* __restrict__ vt) {
  __shared__ __bf16 tile[64][65];
  const int t0 = blockIdx.x * 64;
  const int d0 = blockIdx.y * 64;
  const int kvh = blockIdx.z;
#pragma unroll
  for (int p = 0; p < 16; ++p) {
    int i = p * 256 + threadIdx.x;
    int r = i >> 6;      // t offset
    int c = i & 63;      // d offset (consecutive tid -> coalesced)
    float f = v_ws[(size_t)(t0 + r) * (KVH * D) + kvh * D + d0 + c];
    out_v[((size_t)kvh * T + t0 + r) * D + d0 + c] = f;
    tile[r][c] = (__bf16)f;
  }
  __syncthreads();
#pragma unroll
  for (int p = 0; p < 16; ++p) {
    int i = p * 256 + threadIdx.x;
    int dd = i >> 6;     // d offset
    int tt = i & 63;     // t offset (consecutive tid -> coalesced)
    vt[((size_t)kvh * D + d0 + dd) * T + t0 + tt] = tile[tt][dd];
  }
}

// ---------------- MFMA flash attention, balanced + LDS-staged --------------
// Grid (T/128, H); block bx owns Q-blocks p_lo=bx and p_hi=31-bx (light+heavy
// pairing -> uniform per-block compute). 4 waves; wave w owns 16-row strips
// of BOTH Q-blocks. Per KV step the whole block cooperatively stages K(hi+lo)
// and V tiles into double-buffered LDS (issue loads for t+1 before compute of
// t, ds_write after, ONE barrier per tile). RoPE is applied to Q at load time
// (prologue only; (d,d+64) pair maps to fragment c and c+2 in the same lane).
// NOTE (round-3 post-mortem): defer-max + setprio here caused accumulator
// regalloc collapse -> ~1 GB scratch spill traffic. Keep softmax straight-line.
struct StageRegs { bf16x8 k0, k1, l0, l1, v0, v1; };

__device__ __forceinline__ void stage_load(
    StageRegs& s, const __bf16* __restrict__ Kh, const __bf16* __restrict__ Kl,
    const __bf16* __restrict__ Vt, int j0, int tid) {
  const int kr = tid >> 4, kj = (tid & 15) * 8;
  s.k0 = *(const bf16x8*)(Kh + (size_t)(j0 + kr) * D + kj);
  s.k1 = *(const bf16x8*)(Kh + (size_t)(j0 + kr + 16) * D + kj);
  s.l0 = *(const bf16x8*)(Kl + (size_t)(j0 + kr) * D + kj);
  s.l1 = *(const bf16x8*)(Kl + (size_t)(j0 + kr + 16) * D + kj);
  const int vd = tid >> 2, vj = (tid & 3) * 8;
  s.v0 = *(const bf16x8*)(Vt + (size_t)vd * T + j0 + vj);
  s.v1 = *(const bf16x8*)(Vt + (size_t)(vd + 64) * T + j0 + vj);
}

__device__ __forceinline__ void stage_write(
    const StageRegs& s, __bf16* __restrict__ KhL, __bf16* __restrict__ KlL,
    __bf16* __restrict__ VL, int tid) {
  const int kr = tid >> 4, kj = (tid & 15) * 8;
  *(bf16x8*)(KhL + kr * 136 + kj) = s.k0;
  *(bf16x8*)(KhL + (kr + 16) * 136 + kj) = s.k1;
  *(bf16x8*)(KlL + kr * 136 + kj) = s.l0;
  *(bf16x8*)(KlL + (kr + 16) * 136 + kj) = s.l1;
  const int vd = tid >> 2, vj = (tid & 3) * 8;
  *(bf16x8*)(VL + vd * 40 + vj) = s.v0;
  *(bf16x8*)(VL + (vd + 64) * 40 + vj) = s.v1;
}

// Q load + RoPE + hi/lo split. Lane holds row trow, dims c*32 + quad*8 + jj.
// RoPE pairs d (c=0,1) with d+64 (c=2,3); cos/sin only needed for d<64.
__device__ __forceinline__ void load_q_rope(
    const float* __restrict__ qr, const float* __restrict__ cosb,
    const float* __restrict__ sinb, int trow, int quad,
    bf16x8* __restrict__ qh, bf16x8* __restrict__ ql) {
  float u[4][8];
#pragma unroll
  for (int c = 0; c < 4; ++c) {
    *(float4*)&u[c][0] = *(const float4*)(qr + c * 32 + quad * 8);
    *(float4*)&u[c][4] = *(const float4*)(qr + c * 32 + quad * 8 + 4);
  }
  float cv[2][8], sv[2][8];
#pragma unroll
  for (int c = 0; c < 2; ++c) {
    const float* cp = cosb + (size_t)trow * D + c * 32 + quad * 8;
    const float* sp = sinb + (size_t)trow * D + c * 32 + quad * 8;
    *(float4*)&cv[c][0] = *(const float4*)cp;
    *(float4*)&cv[c][4] = *(const float4*)(cp + 4);
    *(float4*)&sv[c][0] = *(const float4*)sp;
    *(float4*)&sv[c][4] = *(const float4*)(sp + 4);
  }
#pragma unroll
  for (int c = 0; c < 4; ++c) {
    const int cc = c & 1;
#pragma unroll
    for (int jj = 0; jj < 8; ++jj) {
      float r = (c < 2) ? (u[c][jj] * cv[cc][jj] - u[c + 2][jj] * sv[cc][jj])
                        : (u[c][jj] * cv[cc][jj] + u[c - 2][jj] * sv[cc][jj]);
      __bf16 hi = (__bf16)r;
      qh[c][jj] = hi;
      ql[c][jj] = (__bf16)(r - (float)hi);
    }
  }
}

__device__ __forceinline__ void softmax_pv(
    floatx4 s0, floatx4 s1,
    const __bf16* __restrict__ VT, __bf16* __restrict__ Pw,
    floatx4* __restrict__ O, float* __restrict__ m_i, float* __restrict__ l_i,
    int j0, int r_base, int n16, int quad) {
  // causal mask (wave-uniform branch; C-layout rows r = r_base + quad*4 + i)
  if (j0 + 31 > r_base) {
#pragma unroll
    for (int i = 0; i < 4; ++i) {
      int r = r_base + quad * 4 + i;
      if (j0 + n16 > r) s0[i] = -INFINITY;
      if (j0 + 16 + n16 > r) s1[i] = -INFINITY;
    }
  }
  float p0[4], p1[4];
#pragma unroll
  for (int i = 0; i < 4; ++i) {
    float mt = fmaxf(s0[i], s1[i]);
    mt = fmaxf(mt, __shfl_xor(mt, 1));
    mt = fmaxf(mt, __shfl_xor(mt, 2));
    mt = fmaxf(mt, __shfl_xor(mt, 4));
    mt = fmaxf(mt, __shfl_xor(mt, 8));
    float mn = fmaxf(m_i[i], mt);
    float alpha = __expf(m_i[i] - mn);   // first tile: exp(-inf)=0
    m_i[i] = mn;
    p0[i] = __expf(s0[i] - mn);
    p1[i] = __expf(s1[i] - mn);
    float rs = p0[i] + p1[i];
    rs += __shfl_xor(rs, 1);
    rs += __shfl_xor(rs, 2);
    rs += __shfl_xor(rs, 4);
    rs += __shfl_xor(rs, 8);
    l_i[i] = l_i[i] * alpha + rs;
#pragma unroll
    for (int dt = 0; dt < 8; ++dt) O[dt][i] *= alpha;
  }
  // P: C-layout -> A-layout via per-wave LDS round-trip (no barrier needed)
#pragma unroll
  for (int i = 0; i < 4; ++i) {
    Pw[(quad * 4 + i) * 40 + n16] = (__bf16)p0[i];
    Pw[(quad * 4 + i) * 40 + n16 + 16] = (__bf16)p1[i];
  }
  bf16x8 pA = *(const bf16x8*)(Pw + n16 * 40 + quad * 8);
#pragma unroll
  for (int dt = 0; dt < 8; ++dt) {
    bf16x8 vB = *(const bf16x8*)(VT + (dt * 16 + n16) * 40 + quad * 8);
    O[dt] = MFMA16(pA, vB, O[dt], 0, 0, 0);
  }
}

template <bool BOTH>
__device__ __forceinline__ void attn_tile2(
    const __bf16* __restrict__ KhT, const __bf16* __restrict__ KlT,
    const __bf16* __restrict__ VT, __bf16* __restrict__ Pw,
    const bf16x8* qh_hi, const bf16x8* ql_hi,
    const bf16x8* qh_lo, const bf16x8* ql_lo,
    floatx4* O_hi, float* m_hi, float* l_hi,
    floatx4* O_lo, float* m_lo, float* l_lo,
    int j0, int rb_hi, int rb_lo, int n16, int quad) {
  floatx4 sh0 = {0.f, 0.f, 0.f, 0.f}, sh1 = {0.f, 0.f, 0.f, 0.f};
  floatx4 sl0 = {0.f, 0.f, 0.f, 0.f}, sl1 = {0.f, 0.f, 0.f, 0.f};
#pragma unroll
  for (int c = 0; c < 4; ++c) {
    const int off = c * 32 + quad * 8;
    bf16x8 k0h = *(const bf16x8*)(KhT + n16 * 136 + off);
    bf16x8 k1h = *(const bf16x8*)(KhT + (n16 + 16) * 136 + off);
    bf16x8 k0l = *(const bf16x8*)(KlT + n16 * 136 + off);
    bf16x8 k1l = *(const bf16x8*)(KlT + (n16 + 16) * 136 + off);
    sh0 = MFMA16(qh_hi[c], k0h, sh0, 0, 0, 0);
    sh0 = MFMA16(ql_hi[c], k0h, sh0, 0, 0, 0);
    sh0 = MFMA16(qh_hi[c], k0l, sh0, 0, 0, 0);
    sh1 = MFMA16(qh_hi[c], k1h, sh1, 0, 0, 0);
    sh1 = MFMA16(ql_hi[c], k1h, sh1, 0, 0, 0);
    sh1 = MFMA16(qh_hi[c], k1l, sh1, 0, 0, 0);
    if (BOTH) {
      sl0 = MFMA16(qh_lo[c], k0h, sl0, 0, 0, 0);
      sl0 = MFMA16(ql_lo[c], k0h, sl0, 0, 0, 0);
      sl0 = MFMA16(qh_lo[c], k0l, sl0, 0, 0, 0);
      sl1 = MFMA16(qh_lo[c], k1h, sl1, 0, 0, 0);
      sl1 = MFMA16(ql_lo[c], k1h, sl1, 0, 0, 0);
      sl1 = MFMA16(qh_lo[c], k1l, sl1, 0, 0, 0);
    }
  }
  softmax_pv(sh0, sh1, VT, Pw, O_hi, m_hi, l_hi, j0, rb_hi, n16, quad);
  if (BOTH) softmax_pv(sl0, sl1, VT, Pw, O_lo, m_lo, l_lo, j0, rb_lo, n16, quad);
}

__global__ __launch_bounds__(256, 2) void flash_attn(
    float* __restrict__ q,
    const __bf16* __restrict__ khi,   // [KVH][T][D]
    const __bf16* __restrict__ klo,   // [KVH][T][D]
    const __bf16* __restrict__ vt,    // [KVH][D][T]
    const float* __restrict__ cosb,
    const float* __restrict__ sinb) {
  __shared__ __attribute__((aligned(16))) __bf16 KhL[2][32 * 136];
  __shared__ __attribute__((aligned(16))) __bf16 KlL[2][32 * 136];
  __shared__ __attribute__((aligned(16))) __bf16 VL[2][128 * 40];
  __shared__ __attribute__((aligned(16))) __bf16 Pst[4][16 * 40];

  const int tid = threadIdx.x;
  const int w = tid >> 6;
  const int lane = tid & 63;
  const int n16 = lane & 15;
  const int quad = lane >> 4;
  const int h = blockIdx.y;
  const int kvh = h >> 2;
  const int p_lo = blockIdx.x;         // 0..15
  const int p_hi = 31 - p_lo;          // 16..31
  const int rb_lo = p_lo * 64 + w * 16;
  const int rb_hi = p_hi * 64 + w * 16;
  const int nt = 64 - 2 * p_lo;              // block-uniform loop count
  const int nt_lo = (rb_lo + 15) / 32 + 1;   // wave-uniform strip bounds
  const int nt_hi = (rb_hi + 15) / 32 + 1;

  const __bf16* Kh = khi + (size_t)kvh * T * D;
  const __bf16* Kl = klo + (size_t)kvh * T * D;
  const __bf16* Vt = vt + (size_t)kvh * D * T;

  // Q fragments (both strips) with fused RoPE
  bf16x8 qh_lo[4], ql_lo[4], qh_hi[4], ql_hi[4];
  load_q_rope(q + (size_t)(rb_lo + n16) * C + h * D, cosb, sinb,
              rb_lo + n16, quad, qh_lo, ql_lo);
  load_q_rope(q + (size_t)(rb_hi + n16) * C + h * D, cosb, sinb,
              rb_hi + n16, quad, qh_hi, ql_hi);

  floatx4 O_lo[8], O_hi[8];
#pragma unroll
  for (int dt = 0; dt < 8; ++dt) {
    O_lo[dt] = (floatx4){0.f, 0.f, 0.f, 0.f};
    O_hi[dt] = (floatx4){0.f, 0.f, 0.f, 0.f};
  }
  float m_lo[4] = {-INFINITY, -INFINITY, -INFINITY, -INFINITY};
  float m_hi[4] = {-INFINITY, -INFINITY, -INFINITY, -INFINITY};
  float l_lo[4] = {0.f, 0.f, 0.f, 0.f};
  float l_hi[4] = {0.f, 0.f, 0.f, 0.f};

  // prologue: stage tile 0 into buffer 0
  StageRegs sreg;
  stage_load(sreg, Kh, Kl, Vt, 0, tid);
  stage_write(sreg, KhL[0], KlL[0], VL[0], tid);
  __syncthreads();

  __bf16* Pw = Pst[w];
  for (int t = 0; t < nt; ++t) {
    const int cur = t & 1;
    const int j0 = t * 32;
    if (t + 1 < nt) stage_load(sreg, Kh, Kl, Vt, j0 + 32, tid);   // issue early
    if (t < nt_hi) {                                              // wave-uniform
      if (t < nt_lo)
        attn_tile2<true>(KhL[cur], KlL[cur], VL[cur], Pw,
                         qh_hi, ql_hi, qh_lo, ql_lo,
                         O_hi, m_hi, l_hi, O_lo, m_lo, l_lo,
                         j0, rb_hi, rb_lo, n16, quad);
      else
        attn_tile2<false>(KhL[cur], KlL[cur], VL[cur], Pw,
                          qh_hi, ql_hi, qh_lo, ql_lo,
                          O_hi, m_hi, l_hi, O_lo, m_lo, l_lo,
                          j0, rb_hi, rb_lo, n16, quad);
    }
    if (t + 1 < nt) stage_write(sreg, KhL[cur ^ 1], KlL[cur ^ 1], VL[cur ^ 1], tid);
    __syncthreads();   // writes visible before next compute; readers of cur done
  }

  // epilogue: y = O / l, overwrite q rows in place (both strips)
#pragma unroll
  for (int i = 0; i < 4; ++i) {
    float inv_l = 1.0f / l_lo[i];
    float inv_h = 1.0f / l_hi[i];
    int r_l = rb_lo + quad * 4 + i;
    int r_h = rb_hi + quad * 4 + i;
    float* yl = q + (size_t)r_l * C + h * D + n16;
    float* yh = q + (size_t)r_h * C + h * D + n16;
#pragma unroll
    for (int dt = 0; dt < 8; ++dt) {
      yl[dt * 16] = O_lo[dt][i] * inv_l;
      yh[dt * 16] = O_hi[dt][i] * inv_h;
    }
  }
}

extern "C" void kernel_launch(void* const* d_in, const int* in_sizes, int n_in,
                              void* d_out, int out_size, void* d_ws, size_t ws_size,
                              hipStream_t stream) {
  (void)in_sizes; (void)n_in; (void)out_size; (void)ws_size;
  const float* x    = (const float*)d_in[0];
  const float* Wq   = (const float*)d_in[1];
  const float* Wk   = (const float*)d_in[2];
  const float* Wv   = (const float*)d_in[3];
  const float* Wo   = (const float*)d_in[4];
  const float* cosb = (const float*)d_in[5];
  const float* sinb = (const float*)d_in[6];
  // d_in[7] = mask: unused (causal structure applied exactly)

  // workspace layout (~60 MB)
  float* q_ws = (float*)d_ws;                         // T*C fp32 (q raw, then y in-place)
  float* k_ws = q_ws + (size_t)T * C;                 // T*KVH*D fp32 (k raw)
  float* v_ws = k_ws + (size_t)T * KVH * D;           // T*KVH*D fp32
  __bf16* khi = (__bf16*)(v_ws + (size_t)T * KVH * D);          // 4 MB
  __bf16* klo = khi + (size_t)KVH * T * D;                      // 4 MB
  __bf16* vt  = klo + (size_t)KVH * T * D;                      // 4 MB

  float* out_y = (float*)d_out;
  float* out_k = out_y + (size_t)T * C;
  float* out_v = out_k + (size_t)KVH * T * D;

  dim3 blk(256);
  // fused Q/K/V projections: 768 blocks, 3/CU
  gemm_qkv<<<dim3(48, T / 128), blk, 0, stream>>>(x, Wq, Wk, Wv, q_ws, k_ws, v_ws);
  // conversions + kv outputs (convert_k applies RoPE to k)
  convert_k<<<(KVH * T * 64 + 255) / 256, blk, 0, stream>>>(k_ws, out_k, khi, klo, cosb, sinb);
  convert_v<<<dim3(T / 64, D / 64, KVH), blk, 0, stream>>>(v_ws, out_v, vt);
  // flash attention (RoPE fused into Q load; writes y over q_ws)
  flash_attn<<<dim3(16, H), blk, 0, stream>>>(q_ws, khi, klo, vt, cosb, sinb);
  // output projection: 2-term split (linear path)
  gemm_split_t<2><<<dim3(C / 128, T / 128), blk, 0, stream>>>(q_ws, Wo, out_y, C, C);
}